// Round 16
// baseline (566.207 us; speedup 1.0000x reference)
//
#include <hip/hip_runtime.h>
#include <math.h>

typedef unsigned short u16;
#define CH    8
#define NBINS 1024
#define WW    512

static const size_t PLANE = (size_t)NBINS * WW;   // 524288
static const size_t TENS  = 16 * PLANE;           // 8388608

using bf16x8 = __attribute__((ext_vector_type(8))) short;
using f32x4  = __attribute__((ext_vector_type(4))) float;

__device__ __forceinline__ u16 bfr(float f) {
    union { float f; unsigned u; } x; x.f = f;
    return (u16)((x.u + 0x7FFFu + ((x.u >> 16) & 1u)) >> 16);
}
__device__ __forceinline__ float bf2f(u16 v) {
    union { unsigned u; float f; } x; x.u = ((unsigned)v) << 16; return x.f;
}

// ---------------------------------------------------------------- fp32 -> bf16
__global__ __launch_bounds__(256)
void cvt_k(const float* __restrict__ src, u16* __restrict__ dst, int n4)
{
    int i = blockIdx.x * 256 + threadIdx.x;
    if (i >= n4) return;
    float4 f = ((const float4*)src)[i];
    ushort4 o;
    o.x = bfr(f.x); o.y = bfr(f.y); o.z = bfr(f.z); o.w = bfr(f.w);
    ((ushort4*)dst)[i] = o;
}

// ---------------------------------------------------------------- frame norm -> transposed bf16
__global__ __launch_bounds__(256)
void frame_norm_t(const float* __restrict__ X, const float* __restrict__ gw,
                  const float* __restrict__ gb, u16* __restrict__ O,
                  int useMap, int mc, int cBase)
{
    int lb = blockIdx.x >> 4, wt = blockIdx.x & 15;
    int bc = useMap ? ((lb / mc) * 8 + cBase + (lb % mc)) : lb;
    const float* xb = X + (size_t)bc * PLANE + wt * 32;
    int wi = threadIdx.x & 31, hg = threadIdx.x >> 5;

    float s = 0.f, s2 = 0.f;
    for (int h = hg * 128; h < hg * 128 + 128; ++h) {
        float v = xb[(size_t)h * WW + wi];
        s += v; s2 += v * v;
    }
    __shared__ float sh[2][8][32];
    __shared__ float smean[32], srstd[32];
    sh[0][hg][wi] = s; sh[1][hg][wi] = s2;
    __syncthreads();
    if (threadIdx.x < 32) {
        float ts = 0.f, ts2 = 0.f;
        for (int g = 0; g < 8; ++g) { ts += sh[0][g][threadIdx.x]; ts2 += sh[1][g][threadIdx.x]; }
        float mean = ts * (1.f / 1024.f);
        float var  = ts2 * (1.f / 1024.f) - mean * mean;
        smean[threadIdx.x] = mean;
        srstd[threadIdx.x] = rsqrtf(var + 1e-5f);
    }
    __syncthreads();
    float mean = smean[wi], rstd = srstd[wi];
    u16* ob = O + ((size_t)lb * 512 + wt * 32 + wi) * 1024;
    for (int h0 = hg * 128; h0 < hg * 128 + 128; h0 += 4) {
        ushort4 pk;
        float v0 = xb[(size_t)(h0+0) * WW + wi];
        float v1 = xb[(size_t)(h0+1) * WW + wi];
        float v2 = xb[(size_t)(h0+2) * WW + wi];
        float v3 = xb[(size_t)(h0+3) * WW + wi];
        pk.x = bfr((v0 - mean) * rstd * gw[h0+0] + gb[h0+0]);
        pk.y = bfr((v1 - mean) * rstd * gw[h0+1] + gb[h0+1]);
        pk.z = bfr((v2 - mean) * rstd * gw[h0+2] + gb[h0+2]);
        pk.w = bfr((v3 - mean) * rstd * gw[h0+3] + gb[h0+3]);
        *(ushort4*)&ob[h0] = pk;
    }
}

// ---------------------------------------------------------------- conv 1x3 (bf16 in/out, fp32 accum; in-place safe)
__global__ __launch_bounds__(256)
void conv1x3_bf(const u16* __restrict__ P, const float* __restrict__ Wc,
                const float* __restrict__ Bc, u16* __restrict__ O)
{
    int b = blockIdx.x >> 10, h = blockIdx.x & 1023;
    __shared__ float sp[CH][WW + 2];
    __shared__ float sw[CH * CH * 3];
    __shared__ float sb[CH];
    int tid = threadIdx.x;
    #pragma unroll
    for (int i = 0; i < CH; ++i) {
        size_t base = (((size_t)b * CH + i) * NBINS + h) * WW;
        sp[i][1 + tid]       = bf2f(P[base + tid]);
        sp[i][1 + 256 + tid] = bf2f(P[base + 256 + tid]);
    }
    if (tid < CH) { sp[tid][0] = 0.f; sp[tid][WW + 1] = 0.f; sb[tid] = Bc[tid]; }
    if (tid < CH * CH * 3) sw[tid] = Wc[tid];
    __syncthreads();
    #pragma unroll
    for (int o = 0; o < CH; ++o) {
        const float* wo = &sw[o * CH * 3];
        #pragma unroll
        for (int j = 0; j < 2; ++j) {
            int wx = tid + j * 256;
            float acc = sb[o];
            #pragma unroll
            for (int i = 0; i < CH; ++i)
                acc += sp[i][wx] * wo[i*3+0] + sp[i][wx+1] * wo[i*3+1] + sp[i][wx+2] * wo[i*3+2];
            O[(((size_t)b * CH + o) * NBINS + h) * WW + wx] = bfr(acc);
        }
    }
}

// ---------------------------------------------------------------- rotary (bf16 pc) -> QR bf16 (w,d) + VT bf16 (d,w)
__global__ __launch_bounds__(256)
void rotary_qv(const u16* __restrict__ PC, u16* __restrict__ QR,
               u16* __restrict__ VT, int bcn_base)
{
    int bcnl = blockIdx.x >> 4, wt = blockIdx.x & 15;
    int bcn = bcn_base + bcnl;
    int bc = bcn >> 2, n = bcn & 3;
    int w0 = wt * 32;
    __shared__ float tl[32][256 + 1];
    int tid = threadIdx.x;
    const u16* src = PC + ((size_t)bc * NBINS + n * 256) * WW + w0;
    int wi = tid & 31, dbase = tid >> 5;
    for (int rep = 0; rep < 32; ++rep) {
        int d = dbase * 32 + rep;
        u16 v = src[(size_t)d * WW + wi];
        tl[wi][d] = bf2f(v);
        VT[((size_t)bcnl * 256 + d) * 512 + w0 + wi] = v;   // V passthrough
    }
    __syncthreads();
    int dp = tid & 127;
    int wg = tid >> 7;
    bool rot = dp < 64;
    float freq = 0.f;
    if (rot) freq = exp2f(-0.20762050593048203f * (float)dp); // 10000^(-dp/64)
    for (int j = 0; j < 16; ++j) {
        int wl = wg * 16 + j;
        float t1 = tl[wl][2 * dp], t2 = tl[wl][2 * dp + 1];
        float o1, o2;
        if (rot) {
            float ang = (float)(w0 + wl) * freq;
            float sn, cn;
            sincosf(ang, &sn, &cn);
            o1 = t1 * cn - t2 * sn;
            o2 = t2 * cn + t1 * sn;
        } else { o1 = t1; o2 = t2; }
        ushort2 pk; pk.x = bfr(o1); pk.y = bfr(o2);
        *(ushort2*)&QR[((size_t)bcnl * 512 + w0 + wl) * 256 + 2 * dp] = pk;
    }
}

// ---------------------------------------------------------------- fused flash attention, KVBLK=32 (proven R12)
__global__ __launch_bounds__(256)
void flash_attn(const u16* __restrict__ QR, const u16* __restrict__ VT,
                u16* __restrict__ A2)
{
    const int blk = blockIdx.x;
    const int bcnl = blk >> 3, qt = blk & 7;
    const int nh = bcnl & 3;

    __shared__ u16 Ks[32 * 256];
    __shared__ u16 Vs[256 * 32];
    __shared__ u16 Ps[4][16 * 40];

    const int tid = threadIdx.x;
    const int wv = tid >> 6, l = tid & 63;
    const int lr = l & 15, lk = l >> 4;
    const int q0w = qt * 64 + wv * 16;

    const char* QRb = (const char*)(QR + (size_t)bcnl * 131072);
    const char* VTb = (const char*)(VT + (size_t)bcnl * 131072);

    bf16x8 qf[8];
    #pragma unroll
    for (int dk = 0; dk < 8; ++dk)
        qf[dk] = *(const bf16x8*)(QRb + ((size_t)(q0w + lr) * 512 + dk * 64 + lk * 16));

    f32x4 acc[16];
    #pragma unroll
    for (int i = 0; i < 16; ++i) acc[i] = (f32x4){0.f, 0.f, 0.f, 0.f};
    float m_r[4] = {-1e30f, -1e30f, -1e30f, -1e30f};
    float l_r[4] = {0.f, 0.f, 0.f, 0.f};

    for (int kt = 0; kt < 16; ++kt) {
        __syncthreads();
        #pragma unroll
        for (int it = 0; it < 4; ++it) {
            int chunk = it * 256 + tid;
            int row = chunk >> 5, cb = chunk & 31;
            int cbg = cb ^ (row & 7);
            const char* s = QRb + ((size_t)(kt * 32 + row) * 512 + cbg * 16);
            char* d = (char*)Ks + (size_t)chunk * 16;
            __builtin_amdgcn_global_load_lds((const __attribute__((address_space(1))) void*)s,
                                             (__attribute__((address_space(3))) void*)d, 16, 0, 0);
        }
        #pragma unroll
        for (int it = 0; it < 4; ++it) {
            int chunk = it * 256 + tid;
            int row = chunk >> 2, cb = chunk & 3;
            int cbg = cb ^ (row & 3);
            const char* s = VTb + ((size_t)row * 1024 + kt * 64 + cbg * 16);
            char* d = (char*)Vs + (size_t)chunk * 16;
            __builtin_amdgcn_global_load_lds((const __attribute__((address_space(1))) void*)s,
                                             (__attribute__((address_space(3))) void*)d, 16, 0, 0);
        }
        __syncthreads();

        f32x4 s4[2];
        #pragma unroll
        for (int n = 0; n < 2; ++n) s4[n] = (f32x4){0.f, 0.f, 0.f, 0.f};
        __builtin_amdgcn_s_setprio(1);
        #pragma unroll
        for (int dk = 0; dk < 8; ++dk) {
            #pragma unroll
            for (int n = 0; n < 2; ++n) {
                int row = n * 16 + lr;
                int off = row * 512 + ((dk * 64 + lk * 16) ^ ((row & 7) << 4));
                bf16x8 kv = *(const bf16x8*)((const char*)Ks + off);
                s4[n] = __builtin_amdgcn_mfma_f32_16x16x32_bf16(qf[dk], kv, s4[n], 0, 0, 0);
            }
        }
        __builtin_amdgcn_s_setprio(0);

        float alpha[4];
        #pragma unroll
        for (int r = 0; r < 4; ++r) {
            float v = fmaxf(s4[0][r], s4[1][r]);
            v = fmaxf(v, __shfl_xor(v, 1));
            v = fmaxf(v, __shfl_xor(v, 2));
            v = fmaxf(v, __shfl_xor(v, 4));
            v = fmaxf(v, __shfl_xor(v, 8));
            float mn = fmaxf(m_r[r], v * 0.03125f);
            alpha[r] = __expf(m_r[r] - mn);
            m_r[r] = mn;
        }
        float psum[4] = {0.f, 0.f, 0.f, 0.f};
        #pragma unroll
        for (int n = 0; n < 2; ++n)
            #pragma unroll
            for (int r = 0; r < 4; ++r) {
                float p = __expf(s4[n][r] * 0.03125f - m_r[r]);
                psum[r] += p;
                Ps[wv][(lk * 4 + r) * 40 + n * 16 + lr] = bfr(p);
            }
        #pragma unroll
        for (int r = 0; r < 4; ++r) {
            float v = psum[r];
            v += __shfl_xor(v, 1); v += __shfl_xor(v, 2);
            v += __shfl_xor(v, 4); v += __shfl_xor(v, 8);
            l_r[r] = l_r[r] * alpha[r] + v;
        }
        #pragma unroll
        for (int df = 0; df < 16; ++df)
            #pragma unroll
            for (int r = 0; r < 4; ++r)
                acc[df][r] *= alpha[r];

        bf16x8 pf = *(const bf16x8*)((const char*)&Ps[wv][0] + lr * 80 + lk * 16);
        __builtin_amdgcn_s_setprio(1);
        #pragma unroll
        for (int df = 0; df < 16; ++df) {
            int row = df * 16 + lr;
            int off = row * 64 + ((lk * 16) ^ ((row & 3) << 4));
            bf16x8 vv = *(const bf16x8*)((const char*)Vs + off);
            acc[df] = __builtin_amdgcn_mfma_f32_16x16x32_bf16(pf, vv, acc[df], 0, 0, 0);
        }
        __builtin_amdgcn_s_setprio(0);
    }

    float invl[4];
    #pragma unroll
    for (int r = 0; r < 4; ++r) invl[r] = 1.f / l_r[r];
    u16* A2b = A2 + (size_t)(bcnl >> 2) * 524288 + (size_t)nh * 256;
    #pragma unroll
    for (int df = 0; df < 16; ++df)
        #pragma unroll
        for (int r = 0; r < 4; ++r) {
            int q = q0w + lk * 4 + r;
            int d = df * 16 + lr;
            A2b[(size_t)q * 1024 + d] = bfr(acc[df][r] * invl[r]);
        }
}

// ---------------------------------------------------------------- bf16 MFMA GEMM (NT), 128x128 tile, 8 waves (R15)
// 512 thr / 8 waves (2M x 4N, 64x32 per wave = 16-MFMA cluster). SPLITK>1:
// grid multiplied, each slice covers K/SPLITK; MODE 5 epilogue atomicAdds
// partial products into C (used for grid-limited lin2: 2 -> 4 blocks/CU).
// Failed (do not repeat): R6 BK64 dbuf, R7 128x128@256thr, R8/R10 in-loop
// fp32-A cvt, R11 cvt-tail, R13 BK32 dbuf.
// MODE 0: C fp32 = acc*scale; 1: C bf16; 2: CT bf16 = relu(acc)^2 (ldC=M);
// MODE 3: C fp32 += acc; 4: C fp32 = Xres + acc; 5: atomicAdd(C, acc).
template<int MODE, int SPLITK>
__global__ __launch_bounds__(512)
void gemm_bt(const u16* __restrict__ A, const u16* __restrict__ B,
             void* __restrict__ Cvoid,
             int K, int tilesN, int tilesPerBatch,
             size_t aStride, size_t bStride,
             int aAdd, int aMod,
             int cDiv, size_t cMul1, size_t cMul2, size_t cAdd2,
             int ldC, float scale, const float* __restrict__ Xres)
{
    int swz;
    {
        const int nwg = gridDim.x;
        const int q = nwg >> 3, r = nwg & 7;
        const int xcd = blockIdx.x & 7, idx = blockIdx.x >> 3;
        swz = (xcd < r ? xcd * (q + 1) : r * (q + 1) + (xcd - r) * q) + idx;
    }
    const int b2 = swz / tilesPerBatch;
    const int t  = swz % tilesPerBatch;
    const int batch = (SPLITK > 1) ? (b2 / SPLITK) : b2;
    const int ks    = (SPLITK > 1) ? (b2 % SPLITK) : 0;
    const int tm = t / tilesN, tn = t % tilesN;
    const int aIdx = (batch + aAdd) % aMod;
    const size_t cOff = cMul1 * (size_t)(batch / cDiv) + cMul2 * (size_t)(batch % cDiv) + cAdd2;

    const u16* Ab = A + (size_t)aIdx * aStride + (size_t)(tm * 128) * K;
    const u16* Bb = B + (size_t)batch * bStride + (size_t)(tn * 128) * K;

    __shared__ u16 As[128 * 64];
    __shared__ u16 Bs[128 * 64];

    const int tid = threadIdx.x;
    const int wv = tid >> 6, l = tid & 63;
    const int wm = wv >> 2, wn = wv & 3;      // 2M x 4N waves
    const int lr = l & 15, lk = l >> 4;

    f32x4 acc[4][2];
    #pragma unroll
    for (int i = 0; i < 4; ++i)
        #pragma unroll
        for (int j = 0; j < 2; ++j)
            acc[i][j] = (f32x4){0.f, 0.f, 0.f, 0.f};

    const int kBeg = ks * (K / SPLITK);
    const int kEnd = kBeg + K / SPLITK;
    for (int k0 = kBeg; k0 < kEnd; k0 += 64) {
        __syncthreads();
        #pragma unroll
        for (int it = 0; it < 2; ++it) {          // A: 1024 chunks of 16B
            int chunk = it * 512 + tid;
            int row = chunk >> 3, cb = chunk & 7;
            int cbg = cb ^ (row & 7);
            const char* sa = (const char*)Ab + ((size_t)row * K + k0 + cbg * 8) * 2;
            char* da = (char*)As + (size_t)chunk * 16;
            __builtin_amdgcn_global_load_lds((const __attribute__((address_space(1))) void*)sa,
                                             (__attribute__((address_space(3))) void*)da, 16, 0, 0);
        }
        #pragma unroll
        for (int it = 0; it < 2; ++it) {          // B: 1024 chunks of 16B
            int chunk = it * 512 + tid;
            int row = chunk >> 3, cb = chunk & 7;
            int cbg = cb ^ (row & 7);
            const char* sb = (const char*)Bb + ((size_t)row * K + k0 + cbg * 8) * 2;
            char* db = (char*)Bs + (size_t)chunk * 16;
            __builtin_amdgcn_global_load_lds((const __attribute__((address_space(1))) void*)sb,
                                             (__attribute__((address_space(3))) void*)db, 16, 0, 0);
        }
        __syncthreads();
        #pragma unroll
        for (int kk = 0; kk < 2; ++kk) {
            bf16x8 av[4], bv[2];
            #pragma unroll
            for (int mi = 0; mi < 4; ++mi) {
                int row = wm * 64 + mi * 16 + lr;
                int off = row * 128 + (((kk << 6) | (lk << 4)) ^ ((row & 7) << 4));
                av[mi] = *(const bf16x8*)((const char*)As + off);
            }
            #pragma unroll
            for (int ni = 0; ni < 2; ++ni) {
                int row = wn * 32 + ni * 16 + lr;
                int off = row * 128 + (((kk << 6) | (lk << 4)) ^ ((row & 7) << 4));
                bv[ni] = *(const bf16x8*)((const char*)Bs + off);
            }
            #pragma unroll
            for (int mi = 0; mi < 4; ++mi)
                #pragma unroll
                for (int ni = 0; ni < 2; ++ni)
                    acc[mi][ni] = __builtin_amdgcn_mfma_f32_16x16x32_bf16(
                        av[mi], bv[ni], acc[mi][ni], 0, 0, 0);
        }
    }

    const int rowBase = tm * 128 + wm * 64;
    const int colBase = tn * 128 + wn * 32;
    if (MODE == 0) {
        float* Cf = (float*)Cvoid;
        #pragma unroll
        for (int mi = 0; mi < 4; ++mi)
            #pragma unroll
            for (int ni = 0; ni < 2; ++ni) {
                int r0 = rowBase + mi * 16 + lk * 4;
                int c  = colBase + ni * 16 + lr;
                #pragma unroll
                for (int r = 0; r < 4; ++r)
                    Cf[cOff + (size_t)(r0 + r) * ldC + c] = acc[mi][ni][r] * scale;
            }
    } else if (MODE == 1) {
        u16* Cb = (u16*)Cvoid;
        #pragma unroll
        for (int mi = 0; mi < 4; ++mi)
            #pragma unroll
            for (int ni = 0; ni < 2; ++ni) {
                int r0 = rowBase + mi * 16 + lk * 4;
                int c  = colBase + ni * 16 + lr;
                #pragma unroll
                for (int r = 0; r < 4; ++r)
                    Cb[cOff + (size_t)(r0 + r) * ldC + c] = bfr(acc[mi][ni][r]);
            }
    } else if (MODE == 2) {
        u16* Cb = (u16*)Cvoid;
        #pragma unroll
        for (int mi = 0; mi < 4; ++mi)
            #pragma unroll
            for (int ni = 0; ni < 2; ++ni) {
                int r0 = rowBase + mi * 16 + lk * 4;
                int c  = colBase + ni * 16 + lr;
                ushort4 pk;
                float v0 = fmaxf(acc[mi][ni][0], 0.f);
                float v1 = fmaxf(acc[mi][ni][1], 0.f);
                float v2 = fmaxf(acc[mi][ni][2], 0.f);
                float v3 = fmaxf(acc[mi][ni][3], 0.f);
                pk.x = bfr(v0 * v0); pk.y = bfr(v1 * v1);
                pk.z = bfr(v2 * v2); pk.w = bfr(v3 * v3);
                *(ushort4*)&Cb[cOff + (size_t)c * ldC + r0] = pk;
            }
    } else if (MODE == 3) {
        float* Cf = (float*)Cvoid;
        #pragma unroll
        for (int mi = 0; mi < 4; ++mi)
            #pragma unroll
            for (int ni = 0; ni < 2; ++ni) {
                int r0 = rowBase + mi * 16 + lk * 4;
                int c  = colBase + ni * 16 + lr;
                #pragma unroll
                for (int r = 0; r < 4; ++r)
                    Cf[cOff + (size_t)(r0 + r) * ldC + c] += acc[mi][ni][r];
            }
    } else if (MODE == 4) {
        float* Cf = (float*)Cvoid;
        #pragma unroll
        for (int mi = 0; mi < 4; ++mi)
            #pragma unroll
            for (int ni = 0; ni < 2; ++ni) {
                int r0 = rowBase + mi * 16 + lk * 4;
                int c  = colBase + ni * 16 + lr;
                #pragma unroll
                for (int r = 0; r < 4; ++r) {
                    size_t idx = cOff + (size_t)(r0 + r) * ldC + c;
                    Cf[idx] = Xres[idx] + acc[mi][ni][r];
                }
            }
    } else {
        float* Cf = (float*)Cvoid;
        #pragma unroll
        for (int mi = 0; mi < 4; ++mi)
            #pragma unroll
            for (int ni = 0; ni < 2; ++ni) {
                int r0 = rowBase + mi * 16 + lk * 4;
                int c  = colBase + ni * 16 + lr;
                #pragma unroll
                for (int r = 0; r < 4; ++r)
                    atomicAdd(&Cf[cOff + (size_t)(r0 + r) * ldC + c], acc[mi][ni][r]);
            }
    }
}

// ---------------------------------------------------------------- launcher (R15 structure, lin2 split-K)
extern "C" void kernel_launch(void* const* d_in, const int* in_sizes, int n_in,
                              void* d_out, int out_size, void* d_ws, size_t ws_size,
                              hipStream_t stream)
{
    const float* x        = (const float*)d_in[0];
    const float* ln1_w    = (const float*)d_in[1];
    const float* ln1_b    = (const float*)d_in[2];
    const float* q_mcl_w  = (const float*)d_in[3];
    const float* q_conv_w = (const float*)d_in[4];
    const float* q_conv_b = (const float*)d_in[5];
    const float* out_mcl_w= (const float*)d_in[6];
    const float* ln2_w    = (const float*)d_in[7];
    const float* ln2_b    = (const float*)d_in[8];
    const float* lin1_w   = (const float*)d_in[9];
    const float* lin2_w   = (const float*)d_in[10];
    float* OUT = (float*)d_out;
    char*  WB  = (char*)d_ws;

    int ga = 4;
    {   const int cands[5] = {64, 32, 16, 8, 4};
        for (int i = 0; i < 5; ++i)
            if (50331648ull + (size_t)cands[i] * 786432ull <= ws_size) { ga = cands[i]; break; }
    }
    int mc = 1;
    {   const int cands[4] = {8, 4, 2, 1};
        for (int i = 0; i < 4; ++i)
            if ((size_t)cands[i] * 18874368ull <= ws_size) { mc = cands[i]; break; }
    }

    // ---- Phase A: norm1 + q_mcl (-> bf16 PC16) + conv (bf16 in-place)
    u16* QW   = (u16*)WB;                      // 16.8MB
    u16* Z1T  = (u16*)(WB + 16777216);         // 16.8MB
    u16* PC16 = (u16*)(WB + 33554432);         // 16.8MB, persists through B
    cvt_k<<<8192, 256, 0, stream>>>(q_mcl_w, QW, 2097152);
    frame_norm_t<<<256, 256, 0, stream>>>(x, ln1_w, ln1_b, Z1T, 0, 1, 0);
    gemm_bt<1, 1><<<512, 512, 0, stream>>>(QW, Z1T, PC16, 1024, 4, 32,
        1048576, 524288, 0, 8, 1, PLANE, 0, 0, 512, 1.f, nullptr);
    conv1x3_bf<<<2048, 256, 0, stream>>>(PC16, q_conv_w, q_conv_b, PC16);

    // ---- Phase B: attention (rotary -> flash -> out_mcl + residual)
    u16* OW = (u16*)WB;                                      // 16.8MB (reuse QW; Z1T dead)
    u16* QR = (u16*)(WB + 50331648);                         // ga*256KB
    u16* VT = QR + (size_t)ga * 131072;                      // ga*256KB
    u16* A2 = VT + (size_t)ga * 131072;                      // (ga/4)*1MB
    cvt_k<<<8192, 256, 0, stream>>>(out_mcl_w, OW, 2097152);
    {
        const int nG = 64 / ga;
        for (int g = 0; g < nG; ++g) {
            const int bcn0 = g * ga, bc0 = bcn0 / 4;
            rotary_qv<<<ga * 16, 256, 0, stream>>>(PC16, QR, VT, bcn0);
            flash_attn<<<ga * 8, 256, 0, stream>>>(QR, VT, A2);
            gemm_bt<4, 1><<<(ga / 4) * 32, 512, 0, stream>>>(OW, A2, OUT, 1024, 4, 32,
                1048576, 524288, bc0, 8, 1, PLANE, 0, (size_t)bc0 * PLANE, 512, 1.f, x);
        }
    }

    // ---- Phase C: MLP, groups of mc channels (both batches => 2mc local)
    u16* WC  = (u16*)WB;                                        // mc*8.4MB
    u16* Z2T = (u16*)(WB + (size_t)mc * 8388608);               // 2mc*1MB
    u16* HT  = (u16*)(WB + (size_t)mc * 8388608 + (size_t)mc * 2097152); // 2mc*4.2MB
    {
        const int nG = 8 / mc;
        for (int g = 0; g < nG; ++g) {
            const int cBase = g * mc;
            cvt_k<<<mc * 4096, 256, 0, stream>>>(lin1_w + (size_t)cBase * 4194304, WC, mc * 1048576);
            frame_norm_t<<<2 * mc * 16, 256, 0, stream>>>(OUT, ln2_w, ln2_b, Z2T, 1, mc, cBase);
            // lin1: M=4096,N=512,K=1024 -> tiles 32x4, 2mc batches (4 blk/CU, thread-capped)
            gemm_bt<2, 1><<<2 * mc * 128, 512, 0, stream>>>(WC, Z2T, HT, 1024, 4, 128,
                4194304, 524288, 0, mc, 1, 2097152, 0, 0, 4096, 1.f, nullptr);
            cvt_k<<<mc * 4096, 256, 0, stream>>>(lin2_w + (size_t)cBase * 4194304, WC, mc * 1048576);
            // lin2: M=1024,N=512,K=4096, SPLITK=2 -> grid 2x, atomicAdd epilogue
            gemm_bt<5, 2><<<2 * mc * 32 * 2, 512, 0, stream>>>(WC, HT, OUT, 4096, 4, 32,
                4194304, 2097152, 0, mc, mc, 8 * PLANE, PLANE, (size_t)cBase * PLANE, 512, 1.f, nullptr);
        }
    }
}

// Round 17
// 549.826 us; speedup vs baseline: 1.0298x; 1.0298x over previous
//
#include <hip/hip_runtime.h>
#include <math.h>

typedef unsigned short u16;
#define CH    8
#define NBINS 1024
#define WW    512

static const size_t PLANE = (size_t)NBINS * WW;   // 524288
static const size_t TENS  = 16 * PLANE;           // 8388608

using bf16x8 = __attribute__((ext_vector_type(8))) short;
using f32x4  = __attribute__((ext_vector_type(4))) float;

__device__ __forceinline__ u16 bfr(float f) {
    union { float f; unsigned u; } x; x.f = f;
    return (u16)((x.u + 0x7FFFu + ((x.u >> 16) & 1u)) >> 16);
}
__device__ __forceinline__ float bf2f(u16 v) {
    union { unsigned u; float f; } x; x.u = ((unsigned)v) << 16; return x.f;
}

// ---------------------------------------------------------------- fp32 -> bf16
__global__ __launch_bounds__(256)
void cvt_k(const float* __restrict__ src, u16* __restrict__ dst, int n4)
{
    int i = blockIdx.x * 256 + threadIdx.x;
    if (i >= n4) return;
    float4 f = ((const float4*)src)[i];
    ushort4 o;
    o.x = bfr(f.x); o.y = bfr(f.y); o.z = bfr(f.z); o.w = bfr(f.w);
    ((ushort4*)dst)[i] = o;
}

// ---------------------------------------------------------------- frame norm -> transposed bf16
__global__ __launch_bounds__(256)
void frame_norm_t(const float* __restrict__ X, const float* __restrict__ gw,
                  const float* __restrict__ gb, u16* __restrict__ O,
                  int useMap, int mc, int cBase)
{
    int lb = blockIdx.x >> 4, wt = blockIdx.x & 15;
    int bc = useMap ? ((lb / mc) * 8 + cBase + (lb % mc)) : lb;
    const float* xb = X + (size_t)bc * PLANE + wt * 32;
    int wi = threadIdx.x & 31, hg = threadIdx.x >> 5;

    float s = 0.f, s2 = 0.f;
    for (int h = hg * 128; h < hg * 128 + 128; ++h) {
        float v = xb[(size_t)h * WW + wi];
        s += v; s2 += v * v;
    }
    __shared__ float sh[2][8][32];
    __shared__ float smean[32], srstd[32];
    sh[0][hg][wi] = s; sh[1][hg][wi] = s2;
    __syncthreads();
    if (threadIdx.x < 32) {
        float ts = 0.f, ts2 = 0.f;
        for (int g = 0; g < 8; ++g) { ts += sh[0][g][threadIdx.x]; ts2 += sh[1][g][threadIdx.x]; }
        float mean = ts * (1.f / 1024.f);
        float var  = ts2 * (1.f / 1024.f) - mean * mean;
        smean[threadIdx.x] = mean;
        srstd[threadIdx.x] = rsqrtf(var + 1e-5f);
    }
    __syncthreads();
    float mean = smean[wi], rstd = srstd[wi];
    u16* ob = O + ((size_t)lb * 512 + wt * 32 + wi) * 1024;
    for (int h0 = hg * 128; h0 < hg * 128 + 128; h0 += 4) {
        ushort4 pk;
        float v0 = xb[(size_t)(h0+0) * WW + wi];
        float v1 = xb[(size_t)(h0+1) * WW + wi];
        float v2 = xb[(size_t)(h0+2) * WW + wi];
        float v3 = xb[(size_t)(h0+3) * WW + wi];
        pk.x = bfr((v0 - mean) * rstd * gw[h0+0] + gb[h0+0]);
        pk.y = bfr((v1 - mean) * rstd * gw[h0+1] + gb[h0+1]);
        pk.z = bfr((v2 - mean) * rstd * gw[h0+2] + gb[h0+2]);
        pk.w = bfr((v3 - mean) * rstd * gw[h0+3] + gb[h0+3]);
        *(ushort4*)&ob[h0] = pk;
    }
}

// ---------------------------------------------------------------- conv 1x3 (bf16 in/out, fp32 accum; in-place safe)
__global__ __launch_bounds__(256)
void conv1x3_bf(const u16* __restrict__ P, const float* __restrict__ Wc,
                const float* __restrict__ Bc, u16* __restrict__ O)
{
    int b = blockIdx.x >> 10, h = blockIdx.x & 1023;
    __shared__ float sp[CH][WW + 2];
    __shared__ float sw[CH * CH * 3];
    __shared__ float sb[CH];
    int tid = threadIdx.x;
    #pragma unroll
    for (int i = 0; i < CH; ++i) {
        size_t base = (((size_t)b * CH + i) * NBINS + h) * WW;
        sp[i][1 + tid]       = bf2f(P[base + tid]);
        sp[i][1 + 256 + tid] = bf2f(P[base + 256 + tid]);
    }
    if (tid < CH) { sp[tid][0] = 0.f; sp[tid][WW + 1] = 0.f; sb[tid] = Bc[tid]; }
    if (tid < CH * CH * 3) sw[tid] = Wc[tid];
    __syncthreads();
    #pragma unroll
    for (int o = 0; o < CH; ++o) {
        const float* wo = &sw[o * CH * 3];
        #pragma unroll
        for (int j = 0; j < 2; ++j) {
            int wx = tid + j * 256;
            float acc = sb[o];
            #pragma unroll
            for (int i = 0; i < CH; ++i)
                acc += sp[i][wx] * wo[i*3+0] + sp[i][wx+1] * wo[i*3+1] + sp[i][wx+2] * wo[i*3+2];
            O[(((size_t)b * CH + o) * NBINS + h) * WW + wx] = bfr(acc);
        }
    }
}

// ---------------------------------------------------------------- rotary (bf16 pc) -> QR bf16 (w,d) + VT bf16 (d,w)
__global__ __launch_bounds__(256)
void rotary_qv(const u16* __restrict__ PC, u16* __restrict__ QR,
               u16* __restrict__ VT, int bcn_base)
{
    int bcnl = blockIdx.x >> 4, wt = blockIdx.x & 15;
    int bcn = bcn_base + bcnl;
    int bc = bcn >> 2, n = bcn & 3;
    int w0 = wt * 32;
    __shared__ float tl[32][256 + 1];
    int tid = threadIdx.x;
    const u16* src = PC + ((size_t)bc * NBINS + n * 256) * WW + w0;
    int wi = tid & 31, dbase = tid >> 5;
    for (int rep = 0; rep < 32; ++rep) {
        int d = dbase * 32 + rep;
        u16 v = src[(size_t)d * WW + wi];
        tl[wi][d] = bf2f(v);
        VT[((size_t)bcnl * 256 + d) * 512 + w0 + wi] = v;   // V passthrough
    }
    __syncthreads();
    int dp = tid & 127;
    int wg = tid >> 7;
    bool rot = dp < 64;
    float freq = 0.f;
    if (rot) freq = exp2f(-0.20762050593048203f * (float)dp); // 10000^(-dp/64)
    for (int j = 0; j < 16; ++j) {
        int wl = wg * 16 + j;
        float t1 = tl[wl][2 * dp], t2 = tl[wl][2 * dp + 1];
        float o1, o2;
        if (rot) {
            float ang = (float)(w0 + wl) * freq;
            float sn, cn;
            sincosf(ang, &sn, &cn);
            o1 = t1 * cn - t2 * sn;
            o2 = t2 * cn + t1 * sn;
        } else { o1 = t1; o2 = t2; }
        ushort2 pk; pk.x = bfr(o1); pk.y = bfr(o2);
        *(ushort2*)&QR[((size_t)bcnl * 512 + w0 + wl) * 256 + 2 * dp] = pk;
    }
}

// ---------------------------------------------------------------- fused flash attention, KVBLK=32 (proven R12)
__global__ __launch_bounds__(256)
void flash_attn(const u16* __restrict__ QR, const u16* __restrict__ VT,
                u16* __restrict__ A2)
{
    const int blk = blockIdx.x;
    const int bcnl = blk >> 3, qt = blk & 7;
    const int nh = bcnl & 3;

    __shared__ u16 Ks[32 * 256];
    __shared__ u16 Vs[256 * 32];
    __shared__ u16 Ps[4][16 * 40];

    const int tid = threadIdx.x;
    const int wv = tid >> 6, l = tid & 63;
    const int lr = l & 15, lk = l >> 4;
    const int q0w = qt * 64 + wv * 16;

    const char* QRb = (const char*)(QR + (size_t)bcnl * 131072);
    const char* VTb = (const char*)(VT + (size_t)bcnl * 131072);

    bf16x8 qf[8];
    #pragma unroll
    for (int dk = 0; dk < 8; ++dk)
        qf[dk] = *(const bf16x8*)(QRb + ((size_t)(q0w + lr) * 512 + dk * 64 + lk * 16));

    f32x4 acc[16];
    #pragma unroll
    for (int i = 0; i < 16; ++i) acc[i] = (f32x4){0.f, 0.f, 0.f, 0.f};
    float m_r[4] = {-1e30f, -1e30f, -1e30f, -1e30f};
    float l_r[4] = {0.f, 0.f, 0.f, 0.f};

    for (int kt = 0; kt < 16; ++kt) {
        __syncthreads();
        #pragma unroll
        for (int it = 0; it < 4; ++it) {
            int chunk = it * 256 + tid;
            int row = chunk >> 5, cb = chunk & 31;
            int cbg = cb ^ (row & 7);
            const char* s = QRb + ((size_t)(kt * 32 + row) * 512 + cbg * 16);
            char* d = (char*)Ks + (size_t)chunk * 16;
            __builtin_amdgcn_global_load_lds((const __attribute__((address_space(1))) void*)s,
                                             (__attribute__((address_space(3))) void*)d, 16, 0, 0);
        }
        #pragma unroll
        for (int it = 0; it < 4; ++it) {
            int chunk = it * 256 + tid;
            int row = chunk >> 2, cb = chunk & 3;
            int cbg = cb ^ (row & 3);
            const char* s = VTb + ((size_t)row * 1024 + kt * 64 + cbg * 16);
            char* d = (char*)Vs + (size_t)chunk * 16;
            __builtin_amdgcn_global_load_lds((const __attribute__((address_space(1))) void*)s,
                                             (__attribute__((address_space(3))) void*)d, 16, 0, 0);
        }
        __syncthreads();

        f32x4 s4[2];
        #pragma unroll
        for (int n = 0; n < 2; ++n) s4[n] = (f32x4){0.f, 0.f, 0.f, 0.f};
        __builtin_amdgcn_s_setprio(1);
        #pragma unroll
        for (int dk = 0; dk < 8; ++dk) {
            #pragma unroll
            for (int n = 0; n < 2; ++n) {
                int row = n * 16 + lr;
                int off = row * 512 + ((dk * 64 + lk * 16) ^ ((row & 7) << 4));
                bf16x8 kv = *(const bf16x8*)((const char*)Ks + off);
                s4[n] = __builtin_amdgcn_mfma_f32_16x16x32_bf16(qf[dk], kv, s4[n], 0, 0, 0);
            }
        }
        __builtin_amdgcn_s_setprio(0);

        float alpha[4];
        #pragma unroll
        for (int r = 0; r < 4; ++r) {
            float v = fmaxf(s4[0][r], s4[1][r]);
            v = fmaxf(v, __shfl_xor(v, 1));
            v = fmaxf(v, __shfl_xor(v, 2));
            v = fmaxf(v, __shfl_xor(v, 4));
            v = fmaxf(v, __shfl_xor(v, 8));
            float mn = fmaxf(m_r[r], v * 0.03125f);
            alpha[r] = __expf(m_r[r] - mn);
            m_r[r] = mn;
        }
        float psum[4] = {0.f, 0.f, 0.f, 0.f};
        #pragma unroll
        for (int n = 0; n < 2; ++n)
            #pragma unroll
            for (int r = 0; r < 4; ++r) {
                float p = __expf(s4[n][r] * 0.03125f - m_r[r]);
                psum[r] += p;
                Ps[wv][(lk * 4 + r) * 40 + n * 16 + lr] = bfr(p);
            }
        #pragma unroll
        for (int r = 0; r < 4; ++r) {
            float v = psum[r];
            v += __shfl_xor(v, 1); v += __shfl_xor(v, 2);
            v += __shfl_xor(v, 4); v += __shfl_xor(v, 8);
            l_r[r] = l_r[r] * alpha[r] + v;
        }
        #pragma unroll
        for (int df = 0; df < 16; ++df)
            #pragma unroll
            for (int r = 0; r < 4; ++r)
                acc[df][r] *= alpha[r];

        bf16x8 pf = *(const bf16x8*)((const char*)&Ps[wv][0] + lr * 80 + lk * 16);
        __builtin_amdgcn_s_setprio(1);
        #pragma unroll
        for (int df = 0; df < 16; ++df) {
            int row = df * 16 + lr;
            int off = row * 64 + ((lk * 16) ^ ((row & 3) << 4));
            bf16x8 vv = *(const bf16x8*)((const char*)Vs + off);
            acc[df] = __builtin_amdgcn_mfma_f32_16x16x32_bf16(pf, vv, acc[df], 0, 0, 0);
        }
        __builtin_amdgcn_s_setprio(0);
    }

    float invl[4];
    #pragma unroll
    for (int r = 0; r < 4; ++r) invl[r] = 1.f / l_r[r];
    u16* A2b = A2 + (size_t)(bcnl >> 2) * 524288 + (size_t)nh * 256;
    #pragma unroll
    for (int df = 0; df < 16; ++df)
        #pragma unroll
        for (int r = 0; r < 4; ++r) {
            int q = q0w + lk * 4 + r;
            int d = df * 16 + lr;
            A2b[(size_t)q * 1024 + d] = bfr(acc[df][r] * invl[r]);
        }
}

// ---------------------------------------------------------------- bf16 MFMA GEMM (NT), 128x128 tile, 8 waves (FINAL, R15)
// 512 thr / 8 waves (2M x 4N, 64x32 per wave = 16-MFMA cluster), 2-barrier
// single-buffer schedule, global_load_lds + XOR swizzle, XCD-chunked
// bijective block swizzle. Measured optimum of this structure family —
// failed variants (do not repeat): R6 BK64 dbuf (-26%), R7 128x128@256thr
// (-12%), R8/R10 in-loop fp32-A cvt (-60..190us), R11 cvt-tail overlap,
// R13 BK32 dbuf (-20%), R16 split-K atomicAdd (-16us, 2x write traffic).
// MODE 0: C fp32 = acc*scale; 1: C bf16; 2: CT bf16 = relu(acc)^2 (ldC=M);
// MODE 3: C fp32 += acc; 4: C fp32 = Xres + acc.
template<int MODE>
__global__ __launch_bounds__(512)
void gemm_bt(const u16* __restrict__ A, const u16* __restrict__ B,
             void* __restrict__ Cvoid,
             int K, int tilesN, int tilesPerBatch,
             size_t aStride, size_t bStride,
             int aAdd, int aMod,
             int cDiv, size_t cMul1, size_t cMul2, size_t cAdd2,
             int ldC, float scale, const float* __restrict__ Xres)
{
    int swz;
    {
        const int nwg = gridDim.x;
        const int q = nwg >> 3, r = nwg & 7;
        const int xcd = blockIdx.x & 7, idx = blockIdx.x >> 3;
        swz = (xcd < r ? xcd * (q + 1) : r * (q + 1) + (xcd - r) * q) + idx;
    }
    const int batch = swz / tilesPerBatch;
    const int t  = swz % tilesPerBatch;
    const int tm = t / tilesN, tn = t % tilesN;
    const int aIdx = (batch + aAdd) % aMod;
    const size_t cOff = cMul1 * (size_t)(batch / cDiv) + cMul2 * (size_t)(batch % cDiv) + cAdd2;

    const u16* Ab = A + (size_t)aIdx * aStride + (size_t)(tm * 128) * K;
    const u16* Bb = B + (size_t)batch * bStride + (size_t)(tn * 128) * K;

    __shared__ u16 As[128 * 64];
    __shared__ u16 Bs[128 * 64];

    const int tid = threadIdx.x;
    const int wv = tid >> 6, l = tid & 63;
    const int wm = wv >> 2, wn = wv & 3;      // 2M x 4N waves
    const int lr = l & 15, lk = l >> 4;

    f32x4 acc[4][2];
    #pragma unroll
    for (int i = 0; i < 4; ++i)
        #pragma unroll
        for (int j = 0; j < 2; ++j)
            acc[i][j] = (f32x4){0.f, 0.f, 0.f, 0.f};

    for (int k0 = 0; k0 < K; k0 += 64) {
        __syncthreads();
        #pragma unroll
        for (int it = 0; it < 2; ++it) {          // A: 1024 chunks of 16B
            int chunk = it * 512 + tid;
            int row = chunk >> 3, cb = chunk & 7;
            int cbg = cb ^ (row & 7);
            const char* sa = (const char*)Ab + ((size_t)row * K + k0 + cbg * 8) * 2;
            char* da = (char*)As + (size_t)chunk * 16;
            __builtin_amdgcn_global_load_lds((const __attribute__((address_space(1))) void*)sa,
                                             (__attribute__((address_space(3))) void*)da, 16, 0, 0);
        }
        #pragma unroll
        for (int it = 0; it < 2; ++it) {          // B: 1024 chunks of 16B
            int chunk = it * 512 + tid;
            int row = chunk >> 3, cb = chunk & 7;
            int cbg = cb ^ (row & 7);
            const char* sb = (const char*)Bb + ((size_t)row * K + k0 + cbg * 8) * 2;
            char* db = (char*)Bs + (size_t)chunk * 16;
            __builtin_amdgcn_global_load_lds((const __attribute__((address_space(1))) void*)sb,
                                             (__attribute__((address_space(3))) void*)db, 16, 0, 0);
        }
        __syncthreads();
        #pragma unroll
        for (int kk = 0; kk < 2; ++kk) {
            bf16x8 av[4], bv[2];
            #pragma unroll
            for (int mi = 0; mi < 4; ++mi) {
                int row = wm * 64 + mi * 16 + lr;
                int off = row * 128 + (((kk << 6) | (lk << 4)) ^ ((row & 7) << 4));
                av[mi] = *(const bf16x8*)((const char*)As + off);
            }
            #pragma unroll
            for (int ni = 0; ni < 2; ++ni) {
                int row = wn * 32 + ni * 16 + lr;
                int off = row * 128 + (((kk << 6) | (lk << 4)) ^ ((row & 7) << 4));
                bv[ni] = *(const bf16x8*)((const char*)Bs + off);
            }
            #pragma unroll
            for (int mi = 0; mi < 4; ++mi)
                #pragma unroll
                for (int ni = 0; ni < 2; ++ni)
                    acc[mi][ni] = __builtin_amdgcn_mfma_f32_16x16x32_bf16(
                        av[mi], bv[ni], acc[mi][ni], 0, 0, 0);
        }
    }

    const int rowBase = tm * 128 + wm * 64;
    const int colBase = tn * 128 + wn * 32;
    if (MODE == 0) {
        float* Cf = (float*)Cvoid;
        #pragma unroll
        for (int mi = 0; mi < 4; ++mi)
            #pragma unroll
            for (int ni = 0; ni < 2; ++ni) {
                int r0 = rowBase + mi * 16 + lk * 4;
                int c  = colBase + ni * 16 + lr;
                #pragma unroll
                for (int r = 0; r < 4; ++r)
                    Cf[cOff + (size_t)(r0 + r) * ldC + c] = acc[mi][ni][r] * scale;
            }
    } else if (MODE == 1) {
        u16* Cb = (u16*)Cvoid;
        #pragma unroll
        for (int mi = 0; mi < 4; ++mi)
            #pragma unroll
            for (int ni = 0; ni < 2; ++ni) {
                int r0 = rowBase + mi * 16 + lk * 4;
                int c  = colBase + ni * 16 + lr;
                #pragma unroll
                for (int r = 0; r < 4; ++r)
                    Cb[cOff + (size_t)(r0 + r) * ldC + c] = bfr(acc[mi][ni][r]);
            }
    } else if (MODE == 2) {
        u16* Cb = (u16*)Cvoid;
        #pragma unroll
        for (int mi = 0; mi < 4; ++mi)
            #pragma unroll
            for (int ni = 0; ni < 2; ++ni) {
                int r0 = rowBase + mi * 16 + lk * 4;
                int c  = colBase + ni * 16 + lr;
                ushort4 pk;
                float v0 = fmaxf(acc[mi][ni][0], 0.f);
                float v1 = fmaxf(acc[mi][ni][1], 0.f);
                float v2 = fmaxf(acc[mi][ni][2], 0.f);
                float v3 = fmaxf(acc[mi][ni][3], 0.f);
                pk.x = bfr(v0 * v0); pk.y = bfr(v1 * v1);
                pk.z = bfr(v2 * v2); pk.w = bfr(v3 * v3);
                *(ushort4*)&Cb[cOff + (size_t)c * ldC + r0] = pk;
            }
    } else if (MODE == 3) {
        float* Cf = (float*)Cvoid;
        #pragma unroll
        for (int mi = 0; mi < 4; ++mi)
            #pragma unroll
            for (int ni = 0; ni < 2; ++ni) {
                int r0 = rowBase + mi * 16 + lk * 4;
                int c  = colBase + ni * 16 + lr;
                #pragma unroll
                for (int r = 0; r < 4; ++r)
                    Cf[cOff + (size_t)(r0 + r) * ldC + c] += acc[mi][ni][r];
            }
    } else {
        float* Cf = (float*)Cvoid;
        #pragma unroll
        for (int mi = 0; mi < 4; ++mi)
            #pragma unroll
            for (int ni = 0; ni < 2; ++ni) {
                int r0 = rowBase + mi * 16 + lk * 4;
                int c  = colBase + ni * 16 + lr;
                #pragma unroll
                for (int r = 0; r < 4; ++r) {
                    size_t idx = cOff + (size_t)(r0 + r) * ldC + c;
                    Cf[idx] = Xres[idx] + acc[mi][ni][r];
                }
            }
    }
}

// ---------------------------------------------------------------- launcher (FINAL, R15 structure)
extern "C" void kernel_launch(void* const* d_in, const int* in_sizes, int n_in,
                              void* d_out, int out_size, void* d_ws, size_t ws_size,
                              hipStream_t stream)
{
    const float* x        = (const float*)d_in[0];
    const float* ln1_w    = (const float*)d_in[1];
    const float* ln1_b    = (const float*)d_in[2];
    const float* q_mcl_w  = (const float*)d_in[3];
    const float* q_conv_w = (const float*)d_in[4];
    const float* q_conv_b = (const float*)d_in[5];
    const float* out_mcl_w= (const float*)d_in[6];
    const float* ln2_w    = (const float*)d_in[7];
    const float* ln2_b    = (const float*)d_in[8];
    const float* lin1_w   = (const float*)d_in[9];
    const float* lin2_w   = (const float*)d_in[10];
    float* OUT = (float*)d_out;
    char*  WB  = (char*)d_ws;

    int ga = 4;
    {   const int cands[5] = {64, 32, 16, 8, 4};
        for (int i = 0; i < 5; ++i)
            if (50331648ull + (size_t)cands[i] * 786432ull <= ws_size) { ga = cands[i]; break; }
    }
    int mc = 1;
    {   const int cands[4] = {8, 4, 2, 1};
        for (int i = 0; i < 4; ++i)
            if ((size_t)cands[i] * 18874368ull <= ws_size) { mc = cands[i]; break; }
    }

    // ---- Phase A: norm1 + q_mcl (-> bf16 PC16) + conv (bf16 in-place)
    u16* QW   = (u16*)WB;                      // 16.8MB
    u16* Z1T  = (u16*)(WB + 16777216);         // 16.8MB
    u16* PC16 = (u16*)(WB + 33554432);         // 16.8MB, persists through B
    cvt_k<<<8192, 256, 0, stream>>>(q_mcl_w, QW, 2097152);
    frame_norm_t<<<256, 256, 0, stream>>>(x, ln1_w, ln1_b, Z1T, 0, 1, 0);
    gemm_bt<1><<<512, 512, 0, stream>>>(QW, Z1T, PC16, 1024, 4, 32,
        1048576, 524288, 0, 8, 1, PLANE, 0, 0, 512, 1.f, nullptr);
    conv1x3_bf<<<2048, 256, 0, stream>>>(PC16, q_conv_w, q_conv_b, PC16);

    // ---- Phase B: attention (rotary -> flash -> out_mcl + residual)
    u16* OW = (u16*)WB;                                      // 16.8MB (reuse QW; Z1T dead)
    u16* QR = (u16*)(WB + 50331648);                         // ga*256KB
    u16* VT = QR + (size_t)ga * 131072;                      // ga*256KB
    u16* A2 = VT + (size_t)ga * 131072;                      // (ga/4)*1MB
    cvt_k<<<8192, 256, 0, stream>>>(out_mcl_w, OW, 2097152);
    {
        const int nG = 64 / ga;
        for (int g = 0; g < nG; ++g) {
            const int bcn0 = g * ga, bc0 = bcn0 / 4;
            rotary_qv<<<ga * 16, 256, 0, stream>>>(PC16, QR, VT, bcn0);
            flash_attn<<<ga * 8, 256, 0, stream>>>(QR, VT, A2);
            gemm_bt<4><<<(ga / 4) * 32, 512, 0, stream>>>(OW, A2, OUT, 1024, 4, 32,
                1048576, 524288, bc0, 8, 1, PLANE, 0, (size_t)bc0 * PLANE, 512, 1.f, x);
        }
    }

    // ---- Phase C: MLP, groups of mc channels (both batches => 2mc local)
    u16* WC  = (u16*)WB;                                        // mc*8.4MB
    u16* Z2T = (u16*)(WB + (size_t)mc * 8388608);               // 2mc*1MB
    u16* HT  = (u16*)(WB + (size_t)mc * 8388608 + (size_t)mc * 2097152); // 2mc*4.2MB
    {
        const int nG = 8 / mc;
        for (int g = 0; g < nG; ++g) {
            const int cBase = g * mc;
            cvt_k<<<mc * 4096, 256, 0, stream>>>(lin1_w + (size_t)cBase * 4194304, WC, mc * 1048576);
            frame_norm_t<<<2 * mc * 16, 256, 0, stream>>>(OUT, ln2_w, ln2_b, Z2T, 1, mc, cBase);
            // lin1: M=4096,N=512,K=1024 -> tiles 32x4, 2mc batches
            gemm_bt<2><<<2 * mc * 128, 512, 0, stream>>>(WC, Z2T, HT, 1024, 4, 128,
                4194304, 524288, 0, mc, 1, 2097152, 0, 0, 4096, 1.f, nullptr);
            cvt_k<<<mc * 4096, 256, 0, stream>>>(lin2_w + (size_t)cBase * 4194304, WC, mc * 1048576);
            // lin2: M=1024,N=512,K=4096 -> tiles 8x4
            gemm_bt<3><<<2 * mc * 32, 512, 0, stream>>>(WC, HT, OUT, 4096, 4, 32,
                4194304, 2097152, 0, mc, mc, 8 * PLANE, PLANE, (size_t)cBase * PLANE, 512, 1.f, nullptr);
        }
    }
}